// Round 1
// baseline (97.844 us; speedup 1.0000x reference)
//
#include <hip/hip_runtime.h>

#define T_FRAMES 256
#define D_IN 80
#define CCH 256
#define CCEP 222
#define FFT_N 1024
#define HOP 256
#define WINL 512
#define PF_KT 128
#define ZLEN 65536

// ---------------- weight transpose: (Cout, Cin*K) -> (Cin*K, Cout) ----------------
__global__ void transpose_k(const float* __restrict__ w1, const float* __restrict__ w2,
                            const float* __restrict__ w3,
                            float* __restrict__ w1t, float* __restrict__ w2t, float* __restrict__ w3t) {
  int tid = blockIdx.x * blockDim.x + threadIdx.x;
  int stride = gridDim.x * blockDim.x;
  for (int idx = tid; idx < 240 * 256; idx += stride) { int i = idx >> 8, c = idx & 255; w1t[idx] = w1[c * 240 + i]; }
  for (int idx = tid; idx < 768 * 256; idx += stride) { int i = idx >> 8, c = idx & 255; w2t[idx] = w2[c * 768 + i]; }
  for (int idx = tid; idx < 768 * CCEP; idx += stride) { int i = idx / CCEP, c = idx - i * CCEP; w3t[idx] = w3[c * 768 + i]; }
}

// ---------------- conv1: (T,80) -> (T,256), K=3 same, ReLU. 4 frames / block ----------------
__global__ __launch_bounds__(256) void conv1_k(const float* __restrict__ x, const float* __restrict__ w1t,
                                               const float* __restrict__ b1, float* __restrict__ h1) {
  __shared__ float xs[6][D_IN];
  int t0 = blockIdx.x * 4;
  int c = threadIdx.x;
  for (int i = c; i < 6 * D_IN; i += 256) {
    int r = i / D_IN, cin = i - r * D_IN;
    int tt = t0 - 1 + r;
    xs[r][cin] = (tt >= 0 && tt < T_FRAMES) ? x[tt * D_IN + cin] : 0.f;
  }
  __syncthreads();
  float a0 = b1[c], a1 = a0, a2 = a0, a3 = a0;
  int i = 0;
  for (int cin = 0; cin < D_IN; ++cin) {
    #pragma unroll
    for (int k = 0; k < 3; ++k, ++i) {
      float w = w1t[i * 256 + c];
      a0 += xs[k + 0][cin] * w;
      a1 += xs[k + 1][cin] * w;
      a2 += xs[k + 2][cin] * w;
      a3 += xs[k + 3][cin] * w;
    }
  }
  h1[(t0 + 0) * CCH + c] = fmaxf(a0, 0.f);
  h1[(t0 + 1) * CCH + c] = fmaxf(a1, 0.f);
  h1[(t0 + 2) * CCH + c] = fmaxf(a2, 0.f);
  h1[(t0 + 3) * CCH + c] = fmaxf(a3, 0.f);
}

// ---------------- conv2: (T,256) -> (T,256), K=3 same, ReLU. 4 frames / block ----------------
__global__ __launch_bounds__(256) void conv2_k(const float* __restrict__ h1, const float* __restrict__ w2t,
                                               const float* __restrict__ b2, float* __restrict__ h2) {
  __shared__ float hs[6][CCH];
  int t0 = blockIdx.x * 4;
  int c = threadIdx.x;
  for (int i = c; i < 6 * CCH; i += 256) {
    int r = i >> 8, cin = i & 255;
    int tt = t0 - 1 + r;
    hs[r][cin] = (tt >= 0 && tt < T_FRAMES) ? h1[tt * CCH + cin] : 0.f;
  }
  __syncthreads();
  float a0 = b2[c], a1 = a0, a2 = a0, a3 = a0;
  int i = 0;
  for (int cin = 0; cin < CCH; ++cin) {
    #pragma unroll
    for (int k = 0; k < 3; ++k, ++i) {
      float w = w2t[i * 256 + c];
      a0 += hs[k + 0][cin] * w;
      a1 += hs[k + 1][cin] * w;
      a2 += hs[k + 2][cin] * w;
      a3 += hs[k + 3][cin] * w;
    }
  }
  h2[(t0 + 0) * CCH + c] = fmaxf(a0, 0.f);
  h2[(t0 + 1) * CCH + c] = fmaxf(a1, 0.f);
  h2[(t0 + 2) * CCH + c] = fmaxf(a2, 0.f);
  h2[(t0 + 3) * CCH + c] = fmaxf(a3, 0.f);
}

// ---------------- conv3: (T,256) -> (T,222), /quef_norm. 4 frames / block ----------------
__global__ __launch_bounds__(256) void conv3_k(const float* __restrict__ h2, const float* __restrict__ w3t,
                                               const float* __restrict__ b3, const float* __restrict__ quef,
                                               float* __restrict__ ccep) {
  __shared__ float hs[6][CCH];
  int t0 = blockIdx.x * 4;
  int c = threadIdx.x;
  for (int i = c; i < 6 * CCH; i += 256) {
    int r = i >> 8, cin = i & 255;
    int tt = t0 - 1 + r;
    hs[r][cin] = (tt >= 0 && tt < T_FRAMES) ? h2[tt * CCH + cin] : 0.f;
  }
  __syncthreads();
  if (c < CCEP) {
    float a0 = b3[c], a1 = a0, a2 = a0, a3 = a0;
    int i = 0;
    for (int cin = 0; cin < CCH; ++cin) {
      #pragma unroll
      for (int k = 0; k < 3; ++k, ++i) {
        float w = w3t[i * CCEP + c];
        a0 += hs[k + 0][cin] * w;
        a1 += hs[k + 1][cin] * w;
        a2 += hs[k + 2][cin] * w;
        a3 += hs[k + 3][cin] * w;
      }
    }
    float q = quef[c];
    ccep[(t0 + 0) * CCEP + c] = a0 / q;
    ccep[(t0 + 1) * CCEP + c] = a1 / q;
    ccep[(t0 + 2) * CCEP + c] = a2 / q;
    ccep[(t0 + 3) * CCEP + c] = a3 / q;
  }
}

// ---------------- FFT -> 10^(Re/10), phase=Im -> IFFT.real. One block / frame ----------------
__device__ __forceinline__ unsigned br10(unsigned x) { return __brev(x) >> 22; }

__global__ __launch_bounds__(512) void fft_k(const float* __restrict__ ccep, float* __restrict__ imp) {
  __shared__ float re[FFT_N], im[FFT_N];
  int t = blockIdx.x, tid = threadIdx.x;
  // load zero-padded cepstrum (pad=401) in bit-reversed order for DIT
  for (int i = tid; i < FFT_N; i += 512) {
    unsigned q = br10((unsigned)i);
    float v = (q >= 401u && q < 623u) ? ccep[t * CCEP + (int)(q - 401u)] : 0.f;
    re[i] = v; im[i] = 0.f;
  }
  __syncthreads();
  // forward DIT radix-2 (natural-order output)
  for (int s = 1; s <= 10; ++s) {
    int half = 1 << (s - 1);
    int grp = tid >> (s - 1);
    int pos = tid & (half - 1);
    int i1 = (grp << s) + pos;
    int i2 = i1 + half;
    float ang = -6.283185307179586f * (float)pos / (float)(1 << s);
    float sn, cs; sincosf(ang, &sn, &cs);
    float ar = re[i2], ai = im[i2];
    float tr = cs * ar - sn * ai;
    float ti = cs * ai + sn * ar;
    float ur = re[i1], ui = im[i1];
    re[i1] = ur + tr; im[i1] = ui + ti;
    re[i2] = ur - tr; im[i2] = ui - ti;
    __syncthreads();
  }
  // spectral transform: mag = 10^(Re/10), phase = Im
  for (int f = tid; f < FFT_N; f += 512) {
    float mag = exp2f(re[f] * 0.3321928094887362f);
    float ph = im[f];
    float sn, cs; sincosf(ph, &sn, &cs);
    re[f] = mag * cs; im[f] = mag * sn;
  }
  __syncthreads();
  // inverse DIF radix-2 (natural input -> bit-reversed output), e^{+i}
  for (int s = 10; s >= 1; --s) {
    int half = 1 << (s - 1);
    int grp = tid >> (s - 1);
    int pos = tid & (half - 1);
    int i1 = (grp << s) + pos;
    int i2 = i1 + half;
    float ang = 6.283185307179586f * (float)pos / (float)(1 << s);
    float sn, cs; sincosf(ang, &sn, &cs);
    float ur = re[i1], ui = im[i1];
    float vr = re[i2], vi = im[i2];
    re[i1] = ur + vr; im[i1] = ui + vi;
    float dr = ur - vr, di = ui - vi;
    re[i2] = cs * dr - sn * di;
    im[i2] = cs * di + sn * dr;
    __syncthreads();
  }
  const float inv = 1.0f / (float)FFT_N;
  for (int i = tid; i < FFT_N; i += 512) {
    imp[t * FFT_N + (int)br10((unsigned)i)] = re[i] * inv;
  }
}

// ---------------- LTV filter + window. out[t,w] = sum_s frames[t,s]*imp[t,s+511-w] ----------------
__global__ __launch_bounds__(512) void ltv_k(const float* __restrict__ z, const float* __restrict__ imp,
                                             const float* __restrict__ win, float* __restrict__ outw) {
  __shared__ float fr[WINL];
  __shared__ float ip[FFT_N];
  int t = blockIdx.x, w = threadIdx.x;  // 512 threads
  {
    int idx = t * HOP + w - 255;  // frames[t,s] = z[t*HOP + s - 255], bounds-checked
    fr[w] = (idx >= 0 && idx < ZLEN) ? z[idx] : 0.f;
  }
  for (int i = w; i < FFT_N; i += 512) ip[i] = imp[t * FFT_N + i];
  __syncthreads();
  float acc = 0.f;
  int base = 511 - w;
  #pragma unroll 8
  for (int s = 0; s < WINL; ++s) acc += fr[s] * ip[base + s];
  outw[t * WINL + w] = acc * win[w];
}

// ---------------- overlap-add (with circular roll over t) + 128-tap postfilter ----------------
__global__ __launch_bounds__(256) void pf_k(const float* __restrict__ outw, const float* __restrict__ pf_w,
                                            const float* __restrict__ pf_b, float* __restrict__ y) {
  __shared__ float sb[256 + PF_KT - 1];  // s[n0-63 .. n0+256+64)
  __shared__ float wpf[PF_KT];
  int n0 = blockIdx.x * 256;
  for (int i = threadIdx.x; i < 256 + PF_KT - 1; i += 256) {
    int m = n0 - 63 + i;
    float v = 0.f;
    if (m >= 0 && m < ZLEN) {
      int t = m >> 8, j = m & 255;
      v = outw[t * WINL + j] + outw[((t - 1) & 255) * WINL + HOP + j];
    }
    sb[i] = v;
  }
  if (threadIdx.x < PF_KT) wpf[threadIdx.x] = pf_w[threadIdx.x];
  __syncthreads();
  float acc = pf_b[0];
  #pragma unroll 8
  for (int j = 0; j < PF_KT; ++j) acc += sb[threadIdx.x + j] * wpf[j];
  y[n0 + threadIdx.x] = acc;
}

extern "C" void kernel_launch(void* const* d_in, const int* in_sizes, int n_in,
                              void* d_out, int out_size, void* d_ws, size_t ws_size,
                              hipStream_t stream) {
  const float* x      = (const float*)d_in[0];
  const float* z      = (const float*)d_in[1];
  const float* w1     = (const float*)d_in[2];
  const float* b1     = (const float*)d_in[3];
  const float* w2     = (const float*)d_in[4];
  const float* b2     = (const float*)d_in[5];
  const float* w3     = (const float*)d_in[6];
  const float* b3     = (const float*)d_in[7];
  const float* pf_w   = (const float*)d_in[8];
  const float* pf_b   = (const float*)d_in[9];
  const float* quef   = (const float*)d_in[10];
  const float* win    = (const float*)d_in[11];
  float* out = (float*)d_out;
  float* ws  = (float*)d_ws;

  // workspace layout (floats)
  float* w1t  = ws;                 // 240*256   = 61440
  float* w2t  = w1t + 61440;        // 768*256   = 196608
  float* w3t  = w2t + 196608;       // 768*222   = 170496
  float* h1   = w3t + 170496;       // 256*256   = 65536
  float* h2   = h1 + 65536;         // 256*256   = 65536
  float* ccep = h2 + 65536;         // 256*222   = 56832
  float* imp  = ccep + 56832;       // 256*1024  = 262144
  float* outw = imp + 262144;       // 256*512   = 131072

  transpose_k<<<256, 256, 0, stream>>>(w1, w2, w3, w1t, w2t, w3t);
  conv1_k<<<T_FRAMES / 4, 256, 0, stream>>>(x, w1t, b1, h1);
  conv2_k<<<T_FRAMES / 4, 256, 0, stream>>>(h1, w2t, b2, h2);
  conv3_k<<<T_FRAMES / 4, 256, 0, stream>>>(h2, w3t, b3, quef, ccep);
  fft_k<<<T_FRAMES, 512, 0, stream>>>(ccep, imp);
  ltv_k<<<T_FRAMES, 512, 0, stream>>>(z, imp, win, outw);
  pf_k<<<ZLEN / 256, 256, 0, stream>>>(outw, pf_w, pf_b, out);
}

// Round 3
// 57.363 us; speedup vs baseline: 1.7057x; 1.7057x over previous
//
#include <hip/hip_runtime.h>

#define T_FRAMES 256
#define D_IN 80
#define CCH 256
#define CCEP 222
#define FFT_N 1024
#define HOP 256
#define WINL 512
#define PF_KT 128
#define ZLEN 65536

// ---------------- weight transpose: (Cout, Cin*K) -> (Cin*K, Cout) ----------------
__global__ void transpose_k(const float* __restrict__ w1, const float* __restrict__ w2,
                            const float* __restrict__ w3,
                            float* __restrict__ w1t, float* __restrict__ w2t, float* __restrict__ w3t) {
  int tid = blockIdx.x * blockDim.x + threadIdx.x;
  int stride = gridDim.x * blockDim.x;
  for (int idx = tid; idx < 240 * 256; idx += stride) { int i = idx >> 8, c = idx & 255; w1t[idx] = w1[c * 240 + i]; }
  for (int idx = tid; idx < 768 * 256; idx += stride) { int i = idx >> 8, c = idx & 255; w2t[idx] = w2[c * 768 + i]; }
  for (int idx = tid; idx < 768 * CCEP; idx += stride) { int i = idx / CCEP, c = idx - i * CCEP; w3t[idx] = w3[c * 768 + i]; }
}

// ---------------- conv1: (T,80) -> (T,256), K=3 same, ReLU. 4 frames / block ----------------
__global__ __launch_bounds__(256) void conv1_k(const float* __restrict__ x, const float* __restrict__ w1t,
                                               const float* __restrict__ b1, float* __restrict__ h1) {
  __shared__ float xs[6][D_IN];
  int t0 = blockIdx.x * 4;
  int c = threadIdx.x;
  for (int i = c; i < 6 * D_IN; i += 256) {
    int r = i / D_IN, cin = i - r * D_IN;
    int tt = t0 - 1 + r;
    xs[r][cin] = (tt >= 0 && tt < T_FRAMES) ? x[tt * D_IN + cin] : 0.f;
  }
  __syncthreads();
  float a0 = b1[c], a1 = a0, a2 = a0, a3 = a0;
  int i = 0;
  for (int cin = 0; cin < D_IN; ++cin) {
    #pragma unroll
    for (int k = 0; k < 3; ++k, ++i) {
      float w = w1t[i * 256 + c];
      a0 += xs[k + 0][cin] * w;
      a1 += xs[k + 1][cin] * w;
      a2 += xs[k + 2][cin] * w;
      a3 += xs[k + 3][cin] * w;
    }
  }
  h1[(t0 + 0) * CCH + c] = fmaxf(a0, 0.f);
  h1[(t0 + 1) * CCH + c] = fmaxf(a1, 0.f);
  h1[(t0 + 2) * CCH + c] = fmaxf(a2, 0.f);
  h1[(t0 + 3) * CCH + c] = fmaxf(a3, 0.f);
}

// ---------------- conv2 split-K: grid (4 kchunks, 64 tgroups). Partials, no bias/relu ----------------
__global__ __launch_bounds__(256) void conv2_k(const float* __restrict__ h1, const float* __restrict__ w2t,
                                               float* __restrict__ h2part) {
  __shared__ float hs[6][64];
  int kc = blockIdx.x;            // 0..3 : cin chunk of 64
  int t0 = blockIdx.y * 4;
  int c = threadIdx.x;
  int cbase = kc * 64;
  for (int i = c; i < 6 * 64; i += 256) {
    int r = i >> 6, cin = i & 63;
    int tt = t0 - 1 + r;
    hs[r][cin] = (tt >= 0 && tt < T_FRAMES) ? h1[tt * CCH + cbase + cin] : 0.f;
  }
  __syncthreads();
  float a0 = 0.f, a1 = 0.f, a2 = 0.f, a3 = 0.f;
  int i = cbase * 3;
  for (int cin = 0; cin < 64; ++cin) {
    #pragma unroll
    for (int k = 0; k < 3; ++k, ++i) {
      float w = w2t[i * 256 + c];
      a0 += hs[k + 0][cin] * w;
      a1 += hs[k + 1][cin] * w;
      a2 += hs[k + 2][cin] * w;
      a3 += hs[k + 3][cin] * w;
    }
  }
  int ob = (kc << 8);
  h2part[(ob + t0 + 0) * CCH + c] = a0;
  h2part[(ob + t0 + 1) * CCH + c] = a1;
  h2part[(ob + t0 + 2) * CCH + c] = a2;
  h2part[(ob + t0 + 3) * CCH + c] = a3;
}

// ---------------- conv3 split-K: sums h2 partials + bias + relu on load; writes ccep partials ----------------
__global__ __launch_bounds__(256) void conv3_k(const float* __restrict__ h2part, const float* __restrict__ w3t,
                                               const float* __restrict__ b2, float* __restrict__ ccep_part) {
  __shared__ float hs[6][64];
  int kc = blockIdx.x;
  int t0 = blockIdx.y * 4;
  int c = threadIdx.x;
  int cbase = kc * 64;
  for (int i = c; i < 6 * 64; i += 256) {
    int r = i >> 6, cin = i & 63;
    int tt = t0 - 1 + r;
    float v = 0.f;
    if (tt >= 0 && tt < T_FRAMES) {
      int idx = tt * CCH + cbase + cin;
      v = b2[cbase + cin] + h2part[idx] + h2part[65536 + idx] + h2part[131072 + idx] + h2part[196608 + idx];
      v = fmaxf(v, 0.f);
    }
    hs[r][cin] = v;
  }
  __syncthreads();
  if (c < CCEP) {
    float a0 = 0.f, a1 = 0.f, a2 = 0.f, a3 = 0.f;
    int i = cbase * 3;
    for (int cin = 0; cin < 64; ++cin) {
      #pragma unroll
      for (int k = 0; k < 3; ++k, ++i) {
        float w = w3t[i * CCEP + c];
        a0 += hs[k + 0][cin] * w;
        a1 += hs[k + 1][cin] * w;
        a2 += hs[k + 2][cin] * w;
        a3 += hs[k + 3][cin] * w;
      }
    }
    int ob = (kc << 8);
    ccep_part[(ob + t0 + 0) * CCEP + c] = a0;
    ccep_part[(ob + t0 + 1) * CCEP + c] = a1;
    ccep_part[(ob + t0 + 2) * CCEP + c] = a2;
    ccep_part[(ob + t0 + 3) * CCEP + c] = a3;
  }
}

// ---------------- fused FFT -> spectral transform -> IFFT -> LTV filter + window ----------------
__device__ __forceinline__ unsigned br10(unsigned x) { return __brev(x) >> 22; }

__global__ __launch_bounds__(512) void fftltv_k(const float* __restrict__ ccp, const float* __restrict__ b3,
                                                const float* __restrict__ quef, const float* __restrict__ z,
                                                const float* __restrict__ win, float* __restrict__ outw) {
  __shared__ float re[FFT_N], im[FFT_N], ip[FFT_N], fr[WINL];
  int t = blockIdx.x, tid = threadIdx.x;
  // load zero-padded cepstrum (pad=401) in bit-reversed order, summing 4 conv3 partials + bias, /quef
  for (int i = tid; i < FFT_N; i += 512) {
    unsigned q = br10((unsigned)i);
    float v = 0.f;
    if (q >= 401u && q < 623u) {
      int cq = (int)(q - 401u);
      int base = t * CCEP + cq;
      v = (b3[cq] + ccp[base] + ccp[256 * CCEP + base] + ccp[512 * CCEP + base] + ccp[768 * CCEP + base]) / quef[cq];
    }
    re[i] = v; im[i] = 0.f;
  }
  // preload frame samples (independent of FFT state)
  {
    int idx = t * HOP + (int)tid - 255;  // frames[t,s] = z[t*HOP + s - 255]
    fr[tid] = (idx >= 0 && idx < ZLEN) ? z[idx] : 0.f;
  }
  __syncthreads();
  // forward DIT radix-2 (bit-reversed in, natural out)
  #pragma unroll
  for (int s = 1; s <= 10; ++s) {
    int half = 1 << (s - 1);
    int pos = tid & (half - 1);
    int i1 = ((tid >> (s - 1)) << s) + pos;
    int i2 = i1 + half;
    float ang = (-6.283185307179586f / (float)(1 << s)) * (float)pos;
    float sn, cs; __sincosf(ang, &sn, &cs);
    float ar = re[i2], ai = im[i2];
    float tr = cs * ar - sn * ai;
    float ti = cs * ai + sn * ar;
    float ur = re[i1], ui = im[i1];
    re[i1] = ur + tr; im[i1] = ui + ti;
    re[i2] = ur - tr; im[i2] = ui - ti;
    __syncthreads();
  }
  // spectral transform: mag = 10^(Re/10), phase = Im
  for (int f = tid; f < FFT_N; f += 512) {
    float mag = __expf(re[f] * 0.23025850929940457f);
    float sn, cs; __sincosf(im[f], &sn, &cs);
    re[f] = mag * cs; im[f] = mag * sn;
  }
  __syncthreads();
  // inverse DIF radix-2 (natural in, bit-reversed out), e^{+i}
  #pragma unroll
  for (int s = 10; s >= 1; --s) {
    int half = 1 << (s - 1);
    int pos = tid & (half - 1);
    int i1 = ((tid >> (s - 1)) << s) + pos;
    int i2 = i1 + half;
    float ang = (6.283185307179586f / (float)(1 << s)) * (float)pos;
    float sn, cs; __sincosf(ang, &sn, &cs);
    float ur = re[i1], ui = im[i1];
    float vr = re[i2], vi = im[i2];
    re[i1] = ur + vr; im[i1] = ui + vi;
    float dr = ur - vr, di = ui - vi;
    re[i2] = cs * dr - sn * di;
    im[i2] = cs * di + sn * dr;
    __syncthreads();
  }
  const float inv = 1.0f / (float)FFT_N;
  for (int i = tid; i < FFT_N; i += 512) ip[br10((unsigned)i)] = re[i] * inv;
  __syncthreads();
  // LTV: out[t,w] = sum_s fr[s] * ip[s+511-w], then window
  float acc = 0.f;
  int base = 511 - tid;
  #pragma unroll 8
  for (int s = 0; s < WINL; ++s) acc += fr[s] * ip[base + s];
  outw[t * WINL + tid] = acc * win[tid];
}

// ---------------- overlap-add (with circular roll over t) + 128-tap postfilter ----------------
__global__ __launch_bounds__(256) void pf_k(const float* __restrict__ outw, const float* __restrict__ pf_w,
                                            const float* __restrict__ pf_b, float* __restrict__ y) {
  __shared__ float sb[256 + PF_KT - 1];
  __shared__ float wpf[PF_KT];
  int n0 = blockIdx.x * 256;
  for (int i = threadIdx.x; i < 256 + PF_KT - 1; i += 256) {
    int m = n0 - 63 + i;
    float v = 0.f;
    if (m >= 0 && m < ZLEN) {
      int t = m >> 8, j = m & 255;
      v = outw[t * WINL + j] + outw[((t - 1) & 255) * WINL + HOP + j];
    }
    sb[i] = v;
  }
  if (threadIdx.x < PF_KT) wpf[threadIdx.x] = pf_w[threadIdx.x];
  __syncthreads();
  float acc = pf_b[0];
  #pragma unroll 8
  for (int j = 0; j < PF_KT; ++j) acc += sb[threadIdx.x + j] * wpf[j];
  y[n0 + threadIdx.x] = acc;
}

extern "C" void kernel_launch(void* const* d_in, const int* in_sizes, int n_in,
                              void* d_out, int out_size, void* d_ws, size_t ws_size,
                              hipStream_t stream) {
  const float* x      = (const float*)d_in[0];
  const float* z      = (const float*)d_in[1];
  const float* w1     = (const float*)d_in[2];
  const float* b1     = (const float*)d_in[3];
  const float* w2     = (const float*)d_in[4];
  const float* b2     = (const float*)d_in[5];
  const float* w3     = (const float*)d_in[6];
  const float* b3     = (const float*)d_in[7];
  const float* pf_w   = (const float*)d_in[8];
  const float* pf_b   = (const float*)d_in[9];
  const float* quef   = (const float*)d_in[10];
  const float* win    = (const float*)d_in[11];
  float* out = (float*)d_out;
  float* ws  = (float*)d_ws;

  // workspace layout (floats)
  float* w1t  = ws;                 // 240*256   = 61440
  float* w2t  = w1t + 61440;        // 768*256   = 196608
  float* w3t  = w2t + 196608;       // 768*222   = 170496
  float* h1   = w3t + 170496;       // 256*256   = 65536
  float* h2p  = h1 + 65536;         // 4*256*256 = 262144
  float* ccp  = h2p + 262144;       // 4*256*222 = 227328
  float* outw = ccp + 227328;       // 256*512   = 131072

  transpose_k<<<256, 256, 0, stream>>>(w1, w2, w3, w1t, w2t, w3t);
  conv1_k<<<T_FRAMES / 4, 256, 0, stream>>>(x, w1t, b1, h1);
  conv2_k<<<dim3(4, 64), 256, 0, stream>>>(h1, w2t, h2p);
  conv3_k<<<dim3(4, 64), 256, 0, stream>>>(h2p, w3t, b2, ccp);
  fftltv_k<<<T_FRAMES, 512, 0, stream>>>(ccp, b3, quef, z, win, outw);
  pf_k<<<ZLEN / 256, 256, 0, stream>>>(outw, pf_w, pf_b, out);
}